// Round 1
// baseline (2987.926 us; speedup 1.0000x reference)
//
#include <hip/hip_runtime.h>
#include <hip/hip_bf16.h>
#include <cstdint>
#include <cstddef>

// Problem constants
#define NF 128        // F
#define NA_FEA 64     // A
#define N_EDGES 100000
#define N_ANGLES 400000
#define N_CRYST 512
#define KDIM 320      // 2F + A
#define TWOF 256
#define EPS_LN 1e-5f
#define INV_SQRT_2 0.70710678118654752440f

// ---------------- helpers ----------------
__device__ inline unsigned short f2bf(float x) {
    __hip_bfloat16 b = __float2bfloat16(x);
    return *reinterpret_cast<unsigned short*>(&b);
}
__device__ inline float bf2f(__hip_bfloat16 b) { return __bfloat162float(b); }

// ---------------- kernel 1: segment boundaries (sorted crystal_angle_index) ----------------
__global__ void seg_bounds(const int* __restrict__ seg, int* __restrict__ seg_start) {
    int s = blockIdx.x * blockDim.x + threadIdx.x;
    if (s > N_CRYST) return;
    if (s == N_CRYST) { seg_start[N_CRYST] = N_ANGLES; return; }
    int lo = 0, hi = N_ANGLES;
    while (lo < hi) { int mid = (lo + hi) >> 1; if (seg[mid] < s) lo = mid + 1; else hi = mid; }
    seg_start[s] = lo;
}

// ---------------- kernel 2: fused gather + GEMM  h = total @ W_full^T ----------------
// BM=64, BN=64, BK=32; 256 threads; each thread 4x4 micro-tile. fp32 SIMT baseline.
#define BM 64
#define BN 64
#define BK 32
__global__ __launch_bounds__(256) void gemm_gather(
    const float* __restrict__ angle_fea,      // N_ANGLES x 64
    const float* __restrict__ nbr_fea,        // N_EDGES x 128
    const int*   __restrict__ angle_nbr_idx,  // N_ANGLES x 2
    const float* __restrict__ W_full,         // 256 x 320 (row-major)
    __hip_bfloat16* __restrict__ hout)        // N_ANGLES x 256
{
    __shared__ float As[BK][BM + 4];  // [k][m], stride 68 floats (16B-aligned rows)
    __shared__ float Bs[BK][BN + 4];  // [k][n]
    __shared__ int   pair_sh[2 * BM];

    const int tid  = threadIdx.x;
    const int row0 = blockIdx.x * BM;   // 6250 blocks, exact
    const int col0 = blockIdx.y * BN;   // 4 blocks, exact

    if (tid < 2 * BM) pair_sh[tid] = angle_nbr_idx[(size_t)row0 * 2 + tid];
    __syncthreads();

    float acc[4][4] = {};
    const int ty = tid >> 4, tx = tid & 15;
    const int tm4 = ty * 4, tn4 = tx * 4;

    for (int k0 = 0; k0 < KDIM; k0 += BK) {
        // A tile: 64 rows x 32 k. 512 float4-tasks / 256 threads = 2 each.
        #pragma unroll
        for (int it = 0; it < 2; ++it) {
            int task = it * 256 + tid;
            int m    = task >> 3;
            int kl   = (task & 7) * 4;
            int gk   = k0 + kl;
            const float* src;
            if (gk < 64) {
                src = angle_fea + (size_t)(row0 + m) * 64 + gk;
            } else if (gk < 192) {
                src = nbr_fea + (size_t)pair_sh[2 * m] * 128 + (gk - 64);
            } else {
                src = nbr_fea + (size_t)pair_sh[2 * m + 1] * 128 + (gk - 192);
            }
            float4 v = *(const float4*)src;
            As[kl + 0][m] = v.x; As[kl + 1][m] = v.y; As[kl + 2][m] = v.z; As[kl + 3][m] = v.w;
        }
        // B tile: W_full[col0+n][k0+kl .. +3]
        #pragma unroll
        for (int it = 0; it < 2; ++it) {
            int task = it * 256 + tid;
            int n    = task >> 3;
            int kl   = (task & 7) * 4;
            float4 v = *(const float4*)(W_full + (size_t)(col0 + n) * KDIM + k0 + kl);
            Bs[kl + 0][n] = v.x; Bs[kl + 1][n] = v.y; Bs[kl + 2][n] = v.z; Bs[kl + 3][n] = v.w;
        }
        __syncthreads();
        #pragma unroll
        for (int kk = 0; kk < BK; ++kk) {
            float4 a4 = *(const float4*)&As[kk][tm4];
            float4 b4 = *(const float4*)&Bs[kk][tn4];
            float av[4] = {a4.x, a4.y, a4.z, a4.w};
            float bv[4] = {b4.x, b4.y, b4.z, b4.w};
            #pragma unroll
            for (int i = 0; i < 4; ++i)
                #pragma unroll
                for (int j = 0; j < 4; ++j)
                    acc[i][j] += av[i] * bv[j];
        }
        __syncthreads();
    }
    // store bf16, 4 cols packed per 8B store
    #pragma unroll
    for (int i = 0; i < 4; ++i) {
        size_t r = (size_t)(row0 + tm4 + i);
        unsigned int lo = (unsigned int)f2bf(acc[i][0]) | ((unsigned int)f2bf(acc[i][1]) << 16);
        unsigned int hi = (unsigned int)f2bf(acc[i][2]) | ((unsigned int)f2bf(acc[i][3]) << 16);
        uint2* dst = reinterpret_cast<uint2*>(
            reinterpret_cast<unsigned short*>(hout) + r * TWOF + col0 + tn4);
        *dst = make_uint2(lo, hi);
    }
}

// ---------------- kernel 3: per-segment sum / sumsq (columns = threads) ----------------
__global__ __launch_bounds__(256) void seg_stats(
    const __hip_bfloat16* __restrict__ h,
    const int* __restrict__ seg_start,
    float* __restrict__ segSum, float* __restrict__ segSumSq)
{
    int seg   = blockIdx.x;
    int split = blockIdx.y;  // 0..3
    int start = seg_start[seg], end = seg_start[seg + 1];
    int n = end - start;
    if (n <= 0) return;
    int per = (n + 3) >> 2;
    int r0 = start + split * per;
    int r1 = min(r0 + per, end);
    if (r0 >= r1) return;
    int j = threadIdx.x;
    float sum = 0.f, ss = 0.f;
    for (int r = r0; r < r1; ++r) {
        float v = bf2f(h[(size_t)r * TWOF + j]);
        sum += v; ss += v * v;
    }
    atomicAdd(&segSum[seg * TWOF + j], sum);
    atomicAdd(&segSumSq[seg * TWOF + j], ss);
}

// ---------------- kernel 4: finalize mean / rsqrt(var+eps) in place ----------------
__global__ __launch_bounds__(256) void seg_finalize(
    const int* __restrict__ seg_start,
    float* __restrict__ segSum, float* __restrict__ segSumSq)
{
    int seg = blockIdx.x;
    int j = threadIdx.x;
    float cnt = (float)max(seg_start[seg + 1] - seg_start[seg], 1);
    float inv = 1.0f / cnt;
    float mean = segSum[seg * TWOF + j] * inv;
    float var  = segSumSq[seg * TWOF + j] * inv - mean * mean;
    segSum[seg * TWOF + j]   = mean;                 // now holds mean
    segSumSq[seg * TWOF + j] = rsqrtf(var + EPS_LN); // now holds scale
}

// ---------------- kernel 5: per-angle normalize + LN(core) + gate + scatter ----------------
// 1 wave per angle row; 4 rows per 256-thread block; all reductions intra-wave.
__global__ __launch_bounds__(256) void angle_msg(
    const __hip_bfloat16* __restrict__ h,
    const int* __restrict__ seg_idx,        // crystal_angle_index
    const int* __restrict__ angle_nbr_idx,
    const float* __restrict__ segMean, const float* __restrict__ segScale,
    const float* __restrict__ cn_gamma, const float* __restrict__ cn_beta,
    const float* __restrict__ ln_g, const float* __restrict__ ln_b,
    const float* __restrict__ w_mask,
    float* __restrict__ s_acc, float* __restrict__ c_acc)
{
    int row  = blockIdx.x * 4 + (threadIdx.x >> 6);
    int lane = threadIdx.x & 63;
    int seg  = seg_idx[row];
    int src  = angle_nbr_idx[(size_t)row * 2];

    const __hip_bfloat16* hr = h + (size_t)row * TWOF;
    float y[4];
    #pragma unroll
    for (int q = 0; q < 4; ++q) {
        int col = lane + q * 64;
        float v = bf2f(hr[col]);
        float m = segMean[seg * TWOF + col], sc = segScale[seg * TWOF + col];
        y[q] = (v - m) * sc * cn_gamma[col] + cn_beta[col];
    }
    // layer_norm over core = cols [0,128) -> y[0], y[1]
    float sum = y[0] + y[1], ssq = y[0] * y[0] + y[1] * y[1];
    #pragma unroll
    for (int o = 32; o > 0; o >>= 1) { sum += __shfl_xor(sum, o, 64); ssq += __shfl_xor(ssq, o, 64); }
    float mu  = sum * (1.f / 128.f);
    float var = ssq * (1.f / 128.f) - mu * mu;
    float rs  = rsqrtf(var + EPS_LN);
    float ln0 = (y[0] - mu) * rs * ln_g[lane]      + ln_b[lane];
    float ln1 = (y[1] - mu) * rs * ln_g[lane + 64] + ln_b[lane + 64];
    float si0 = ln0 / (1.f + __expf(-ln0));   // silu
    float si1 = ln1 / (1.f + __expf(-ln1));
    // gate = sigmoid(filter . w_mask), filter = cols [128,256) -> y[2], y[3]
    float gp = y[2] * w_mask[lane] + y[3] * w_mask[lane + 64];
    #pragma unroll
    for (int o = 32; o > 0; o >>= 1) gp += __shfl_xor(gp, o, 64);
    float gate = 1.f / (1.f + __expf(-gp));

    atomicAdd(&s_acc[(size_t)src * NF + lane],      gate * si0);
    atomicAdd(&s_acc[(size_t)src * NF + lane + 64], gate * si1);
    if (lane == 0) atomicAdd(&c_acc[src], 1.0f);
}

// ---------------- kernel 6: per-edge LN2 + two residual MLPs + output ----------------
// 1 wave (64 threads) per edge; each lane owns cols lane and lane+64.
__global__ __launch_bounds__(64) void edge_out(
    const float* __restrict__ s_acc, const float* __restrict__ c_acc,
    const float* __restrict__ nbr_fea,
    const float* __restrict__ ln2_g, const float* __restrict__ ln2_b,
    const float* __restrict__ W1a, const float* __restrict__ b1a,
    const float* __restrict__ W2a, const float* __restrict__ b2a,
    const float* __restrict__ W1b, const float* __restrict__ b1b,
    const float* __restrict__ W2b, const float* __restrict__ b2b,
    float* __restrict__ out)
{
    __shared__ __align__(16) float x_sh[NF];
    __shared__ __align__(16) float h1_sh[64];
    int e    = blockIdx.x;
    int lane = threadIdx.x;

    float cnt = c_acc[e];
    float inv = 1.f / fmaxf(cnt, 1.f);
    float x0 = s_acc[(size_t)e * NF + lane] * inv;
    float x1 = s_acc[(size_t)e * NF + 64 + lane] * inv;

    float sum = x0 + x1, ssq = x0 * x0 + x1 * x1;
    #pragma unroll
    for (int o = 32; o > 0; o >>= 1) { sum += __shfl_xor(sum, o, 64); ssq += __shfl_xor(ssq, o, 64); }
    float mu  = sum * (1.f / 128.f);
    float var = ssq * (1.f / 128.f) - mu * mu;
    float rs  = rsqrtf(var + EPS_LN);
    x0 = (x0 - mu) * rs * ln2_g[lane]      + ln2_b[lane];
    x1 = (x1 - mu) * rs * ln2_g[lane + 64] + ln2_b[lane + 64];

    // ---- MLP a ----
    x_sh[lane] = x0; x_sh[lane + 64] = x1;
    __syncthreads();
    {
        float a = b1a[lane];
        const float4* w  = (const float4*)(W1a + (size_t)lane * NF);
        const float4* xs = (const float4*)x_sh;
        #pragma unroll
        for (int t = 0; t < 32; ++t) {
            float4 ww = w[t], xx = xs[t];
            a += ww.x * xx.x + ww.y * xx.y + ww.z * xx.z + ww.w * xx.w;
        }
        h1_sh[lane] = a / (1.f + __expf(-a));
    }
    __syncthreads();
    {
        float a0 = b2a[lane], a1 = b2a[lane + 64];
        const float4* hs = (const float4*)h1_sh;
        const float4* w0 = (const float4*)(W2a + (size_t)lane * 64);
        const float4* w1 = (const float4*)(W2a + (size_t)(lane + 64) * 64);
        #pragma unroll
        for (int t = 0; t < 16; ++t) {
            float4 hh = hs[t], u = w0[t], v = w1[t];
            a0 += u.x * hh.x + u.y * hh.y + u.z * hh.z + u.w * hh.w;
            a1 += v.x * hh.x + v.y * hh.y + v.z * hh.z + v.w * hh.w;
        }
        x0 += a0; x1 += a1;
    }
    __syncthreads();

    // ---- MLP b ----
    x_sh[lane] = x0; x_sh[lane + 64] = x1;
    __syncthreads();
    {
        float a = b1b[lane];
        const float4* w  = (const float4*)(W1b + (size_t)lane * NF);
        const float4* xs = (const float4*)x_sh;
        #pragma unroll
        for (int t = 0; t < 32; ++t) {
            float4 ww = w[t], xx = xs[t];
            a += ww.x * xx.x + ww.y * xx.y + ww.z * xx.z + ww.w * xx.w;
        }
        h1_sh[lane] = a / (1.f + __expf(-a));
    }
    __syncthreads();
    {
        float a0 = b2b[lane], a1 = b2b[lane + 64];
        const float4* hs = (const float4*)h1_sh;
        const float4* w0 = (const float4*)(W2b + (size_t)lane * 64);
        const float4* w1 = (const float4*)(W2b + (size_t)(lane + 64) * 64);
        #pragma unroll
        for (int t = 0; t < 16; ++t) {
            float4 hh = hs[t], u = w0[t], v = w1[t];
            a0 += u.x * hh.x + u.y * hh.y + u.z * hh.z + u.w * hh.w;
            a1 += v.x * hh.x + v.y * hh.y + v.z * hh.z + v.w * hh.w;
        }
        x0 += a0; x1 += a1;
    }

    size_t base = (size_t)e * NF;
    out[base + lane]      = INV_SQRT_2 * (nbr_fea[base + lane] + x0);
    out[base + 64 + lane] = INV_SQRT_2 * (nbr_fea[base + 64 + lane] + x1);
}

// ---------------- workspace layout (bytes) ----------------
//   [0,              524288)   segSum   (512*256 f32)  -> mean after finalize
//   [524288,        1048576)   segSumSq (512*256 f32)  -> scale after finalize
//   [1048576,      52248576)   s_acc    (100000*128 f32)
//   [52248576,     52648576)   c_acc    (100000 f32)
//   --- everything above zeroed each launch ---
//   [52648576,     52652672)   seg_start (513 i32, padded)
//   [52652672,    257452672)   h (400000*256 bf16)

extern "C" void kernel_launch(void* const* d_in, const int* in_sizes, int n_in,
                              void* d_out, int out_size, void* d_ws, size_t ws_size,
                              hipStream_t stream) {
    const float* nbr_fea       = (const float*)d_in[0];
    const float* angle_fea     = (const float*)d_in[1];
    const int*   angle_nbr_idx = (const int*)d_in[2];
    /* d_in[3] crystal_edge_idx: unused by reference */
    const int*   cai           = (const int*)d_in[4];
    const float* W_full        = (const float*)d_in[5];
    const float* W_mask        = (const float*)d_in[6];
    const float* cn_gamma      = (const float*)d_in[7];
    const float* cn_beta       = (const float*)d_in[8];
    const float* ln_core_g     = (const float*)d_in[9];
    const float* ln_core_b     = (const float*)d_in[10];
    const float* ln2_g         = (const float*)d_in[11];
    const float* ln2_b         = (const float*)d_in[12];
    const float* W1a           = (const float*)d_in[13];
    const float* b1a           = (const float*)d_in[14];
    const float* W2a           = (const float*)d_in[15];
    const float* b2a           = (const float*)d_in[16];
    const float* W1b           = (const float*)d_in[17];
    const float* b1b           = (const float*)d_in[18];
    const float* W2b           = (const float*)d_in[19];
    const float* b2b           = (const float*)d_in[20];
    float* out = (float*)d_out;

    char* ws = (char*)d_ws;
    float* segSum    = (float*)(ws + 0);
    float* segSumSq  = (float*)(ws + 524288);
    float* s_acc     = (float*)(ws + 1048576);
    float* c_acc     = (float*)(ws + 52248576);
    int*   seg_start = (int*)  (ws + 52648576);
    __hip_bfloat16* h = (__hip_bfloat16*)(ws + 52652672);

    // zero all atomic accumulators (one contiguous range)
    hipMemsetAsync(ws, 0, 52648576, stream);

    seg_bounds<<<3, 256, 0, stream>>>(cai, seg_start);
    gemm_gather<<<dim3(N_ANGLES / BM, TWOF / BN), 256, 0, stream>>>(
        angle_fea, nbr_fea, angle_nbr_idx, W_full, h);
    seg_stats<<<dim3(N_CRYST, 4), 256, 0, stream>>>(h, seg_start, segSum, segSumSq);
    seg_finalize<<<N_CRYST, 256, 0, stream>>>(seg_start, segSum, segSumSq);
    angle_msg<<<N_ANGLES / 4, 256, 0, stream>>>(
        h, cai, angle_nbr_idx, segSum, segSumSq,
        cn_gamma, cn_beta, ln_core_g, ln_core_b, W_mask, s_acc, c_acc);
    edge_out<<<N_EDGES, 64, 0, stream>>>(
        s_acc, c_acc, nbr_fea, ln2_g, ln2_b,
        W1a, b1a, W2a, b2a, W1b, b1b, W2b, b2b, out);
}

// Round 2
// 1668.559 us; speedup vs baseline: 1.7907x; 1.7907x over previous
//
#include <hip/hip_runtime.h>
#include <hip/hip_bf16.h>
#include <cstdint>
#include <cstddef>

// Problem constants
#define NF 128        // F
#define NA_FEA 64     // A
#define N_EDGES 100000
#define N_ANGLES 400000
#define N_CRYST 512
#define KDIM 320      // 2F + A
#define TWOF 256
#define EPS_LN 1e-5f
#define INV_SQRT_2 0.70710678118654752440f

// ---------------- helpers ----------------
__device__ inline unsigned short f2bf(float x) {
    __hip_bfloat16 b = __float2bfloat16(x);
    return *reinterpret_cast<unsigned short*>(&b);
}
__device__ inline float bf2f(__hip_bfloat16 b) { return __bfloat162float(b); }

// ---------------- kernel 1: segment boundaries (sorted crystal_angle_index) ----------------
__global__ void seg_bounds(const int* __restrict__ seg, int* __restrict__ seg_start) {
    int s = blockIdx.x * blockDim.x + threadIdx.x;
    if (s > N_CRYST) return;
    if (s == N_CRYST) { seg_start[N_CRYST] = N_ANGLES; return; }
    int lo = 0, hi = N_ANGLES;
    while (lo < hi) { int mid = (lo + hi) >> 1; if (seg[mid] < s) lo = mid + 1; else hi = mid; }
    seg_start[s] = lo;
}

// ---------------- kernel 2: fused gather + GEMM  h = total @ W_full^T ----------------
// BM=64, BN=64, BK=32; 256 threads; each thread 4x4 micro-tile. fp32 SIMT baseline.
#define BM 64
#define BN 64
#define BK 32
__global__ __launch_bounds__(256) void gemm_gather(
    const float* __restrict__ angle_fea,      // N_ANGLES x 64
    const float* __restrict__ nbr_fea,        // N_EDGES x 128
    const int*   __restrict__ angle_nbr_idx,  // N_ANGLES x 2
    const float* __restrict__ W_full,         // 256 x 320 (row-major)
    __hip_bfloat16* __restrict__ hout)        // N_ANGLES x 256
{
    __shared__ float As[BK][BM + 4];  // [k][m]
    __shared__ float Bs[BK][BN + 4];  // [k][n]
    __shared__ int   pair_sh[2 * BM];

    const int tid  = threadIdx.x;
    const int row0 = blockIdx.x * BM;   // 6250 blocks, exact
    const int col0 = blockIdx.y * BN;   // 4 blocks, exact

    if (tid < 2 * BM) pair_sh[tid] = angle_nbr_idx[(size_t)row0 * 2 + tid];
    __syncthreads();

    float acc[4][4] = {};
    const int ty = tid >> 4, tx = tid & 15;
    const int tm4 = ty * 4, tn4 = tx * 4;

    for (int k0 = 0; k0 < KDIM; k0 += BK) {
        #pragma unroll
        for (int it = 0; it < 2; ++it) {
            int task = it * 256 + tid;
            int m    = task >> 3;
            int kl   = (task & 7) * 4;
            int gk   = k0 + kl;
            const float* src;
            if (gk < 64) {
                src = angle_fea + (size_t)(row0 + m) * 64 + gk;
            } else if (gk < 192) {
                src = nbr_fea + (size_t)pair_sh[2 * m] * 128 + (gk - 64);
            } else {
                src = nbr_fea + (size_t)pair_sh[2 * m + 1] * 128 + (gk - 192);
            }
            float4 v = *(const float4*)src;
            As[kl + 0][m] = v.x; As[kl + 1][m] = v.y; As[kl + 2][m] = v.z; As[kl + 3][m] = v.w;
        }
        #pragma unroll
        for (int it = 0; it < 2; ++it) {
            int task = it * 256 + tid;
            int n    = task >> 3;
            int kl   = (task & 7) * 4;
            float4 v = *(const float4*)(W_full + (size_t)(col0 + n) * KDIM + k0 + kl);
            Bs[kl + 0][n] = v.x; Bs[kl + 1][n] = v.y; Bs[kl + 2][n] = v.z; Bs[kl + 3][n] = v.w;
        }
        __syncthreads();
        #pragma unroll
        for (int kk = 0; kk < BK; ++kk) {
            float4 a4 = *(const float4*)&As[kk][tm4];
            float4 b4 = *(const float4*)&Bs[kk][tn4];
            float av[4] = {a4.x, a4.y, a4.z, a4.w};
            float bv[4] = {b4.x, b4.y, b4.z, b4.w};
            #pragma unroll
            for (int i = 0; i < 4; ++i)
                #pragma unroll
                for (int j = 0; j < 4; ++j)
                    acc[i][j] += av[i] * bv[j];
        }
        __syncthreads();
    }
    #pragma unroll
    for (int i = 0; i < 4; ++i) {
        size_t r = (size_t)(row0 + tm4 + i);
        unsigned int lo = (unsigned int)f2bf(acc[i][0]) | ((unsigned int)f2bf(acc[i][1]) << 16);
        unsigned int hi = (unsigned int)f2bf(acc[i][2]) | ((unsigned int)f2bf(acc[i][3]) << 16);
        uint2* dst = reinterpret_cast<uint2*>(
            reinterpret_cast<unsigned short*>(hout) + r * TWOF + col0 + tn4);
        *dst = make_uint2(lo, hi);
    }
}

// ---------------- kernel 3: per-segment sum / sumsq ----------------
__global__ __launch_bounds__(256) void seg_stats(
    const __hip_bfloat16* __restrict__ h,
    const int* __restrict__ seg_start,
    float* __restrict__ segSum, float* __restrict__ segSumSq)
{
    int seg   = blockIdx.x;
    int split = blockIdx.y;  // 0..3
    int start = seg_start[seg], end = seg_start[seg + 1];
    int n = end - start;
    if (n <= 0) return;
    int per = (n + 3) >> 2;
    int r0 = start + split * per;
    int r1 = min(r0 + per, end);
    if (r0 >= r1) return;
    int j = threadIdx.x;
    float sum = 0.f, ss = 0.f;
    for (int r = r0; r < r1; ++r) {
        float v = bf2f(h[(size_t)r * TWOF + j]);
        sum += v; ss += v * v;
    }
    atomicAdd(&segSum[seg * TWOF + j], sum);
    atomicAdd(&segSumSq[seg * TWOF + j], ss);
}

// ---------------- kernel 4: finalize mean / rsqrt(var+eps) in place ----------------
__global__ __launch_bounds__(256) void seg_finalize(
    const int* __restrict__ seg_start,
    float* __restrict__ segSum, float* __restrict__ segSumSq)
{
    int seg = blockIdx.x;
    int j = threadIdx.x;
    float cnt = (float)max(seg_start[seg + 1] - seg_start[seg], 1);
    float inv = 1.0f / cnt;
    float mean = segSum[seg * TWOF + j] * inv;
    float var  = segSumSq[seg * TWOF + j] * inv - mean * mean;
    segSum[seg * TWOF + j]   = mean;
    segSumSq[seg * TWOF + j] = rsqrtf(var + EPS_LN);
}

// ---------------- kernel 5: per-angle normalize + LN(core) + gate + scatter ----------------
__global__ __launch_bounds__(256) void angle_msg(
    const __hip_bfloat16* __restrict__ h,
    const int* __restrict__ seg_idx,
    const int* __restrict__ angle_nbr_idx,
    const float* __restrict__ segMean, const float* __restrict__ segScale,
    const float* __restrict__ cn_gamma, const float* __restrict__ cn_beta,
    const float* __restrict__ ln_g, const float* __restrict__ ln_b,
    const float* __restrict__ w_mask,
    float* __restrict__ s_acc, float* __restrict__ c_acc)
{
    int row  = blockIdx.x * 4 + (threadIdx.x >> 6);
    int lane = threadIdx.x & 63;
    int seg  = seg_idx[row];
    int src  = angle_nbr_idx[(size_t)row * 2];

    const __hip_bfloat16* hr = h + (size_t)row * TWOF;
    float y[4];
    #pragma unroll
    for (int q = 0; q < 4; ++q) {
        int col = lane + q * 64;
        float v = bf2f(hr[col]);
        float m = segMean[seg * TWOF + col], sc = segScale[seg * TWOF + col];
        y[q] = (v - m) * sc * cn_gamma[col] + cn_beta[col];
    }
    float sum = y[0] + y[1], ssq = y[0] * y[0] + y[1] * y[1];
    #pragma unroll
    for (int o = 32; o > 0; o >>= 1) { sum += __shfl_xor(sum, o, 64); ssq += __shfl_xor(ssq, o, 64); }
    float mu  = sum * (1.f / 128.f);
    float var = ssq * (1.f / 128.f) - mu * mu;
    float rs  = rsqrtf(var + EPS_LN);
    float ln0 = (y[0] - mu) * rs * ln_g[lane]      + ln_b[lane];
    float ln1 = (y[1] - mu) * rs * ln_g[lane + 64] + ln_b[lane + 64];
    float si0 = ln0 / (1.f + __expf(-ln0));
    float si1 = ln1 / (1.f + __expf(-ln1));
    float gp = y[2] * w_mask[lane] + y[3] * w_mask[lane + 64];
    #pragma unroll
    for (int o = 32; o > 0; o >>= 1) gp += __shfl_xor(gp, o, 64);
    float gate = 1.f / (1.f + __expf(-gp));

    atomicAdd(&s_acc[(size_t)src * NF + lane],      gate * si0);
    atomicAdd(&s_acc[(size_t)src * NF + lane + 64], gate * si1);
    if (lane == 0) atomicAdd(&c_acc[src], 1.0f);
}

// ---------------- kernel 6: edge MLP as blocked GEMM ----------------
// 64 edges/block, 256 threads. LN2 fused (phase 0), weights staged via LDS,
// 4x4 micro-tiles. LDS: x 64x132 + h 64x68 + w 32x68 = 58.5 KB -> 2 blocks/CU.
#define MT 64
__global__ __launch_bounds__(256) void edge_mlp(
    const float* __restrict__ s_acc, const float* __restrict__ c_acc,
    const float* __restrict__ nbr_fea,
    const float* __restrict__ ln2_g, const float* __restrict__ ln2_b,
    const float* __restrict__ W1a, const float* __restrict__ b1a,
    const float* __restrict__ W2a, const float* __restrict__ b2a,
    const float* __restrict__ W1b, const float* __restrict__ b1b,
    const float* __restrict__ W2b, const float* __restrict__ b2b,
    float* __restrict__ out)
{
    __shared__ float x_sh[MT][132];   // edges x 128 feats (+pad)
    __shared__ float h_sh[MT][68];    // edges x 64 hidden (+pad)
    __shared__ float w_sh[32][68];    // k-chunk x 64 n (+pad)

    const int tid  = threadIdx.x;
    const int row0 = blockIdx.x * MT;
    const int ty = tid >> 4, tx = tid & 15;
    const int tm4 = ty * 4, tn4 = tx * 4;

    // ---- phase 0: load nbr_sumed, LN2, into x_sh. 4 threads/edge, 32 feats each.
    {
        int m = tid >> 2;           // 0..63
        int q = tid & 3;            // feature quarter
        int e = min(row0 + m, N_EDGES - 1);
        float inv = 1.f / fmaxf(c_acc[e], 1.f);
        const float4* src = (const float4*)(s_acc + (size_t)e * NF + q * 32);
        float v[32];
        float sum = 0.f, ssq = 0.f;
        #pragma unroll
        for (int t = 0; t < 8; ++t) {
            float4 f = src[t];
            v[4*t+0] = f.x * inv; v[4*t+1] = f.y * inv; v[4*t+2] = f.z * inv; v[4*t+3] = f.w * inv;
        }
        #pragma unroll
        for (int i = 0; i < 32; ++i) { sum += v[i]; ssq += v[i] * v[i]; }
        sum += __shfl_xor(sum, 1, 64); ssq += __shfl_xor(ssq, 1, 64);
        sum += __shfl_xor(sum, 2, 64); ssq += __shfl_xor(ssq, 2, 64);
        float mu  = sum * (1.f / 128.f);
        float var = ssq * (1.f / 128.f) - mu * mu;
        float rs  = rsqrtf(var + EPS_LN);
        #pragma unroll
        for (int i = 0; i < 32; ++i) {
            int col = q * 32 + i;
            x_sh[m][col] = (v[i] - mu) * rs * ln2_g[col] + ln2_b[col];
        }
    }
    __syncthreads();

    const float* W1s[2] = {W1a, W1b};
    const float* b1s[2] = {b1a, b1b};
    const float* W2s[2] = {W2a, W2b};
    const float* b2s[2] = {b2a, b2b};

    #pragma unroll 1
    for (int blk = 0; blk < 2; ++blk) {
        const float* W1 = W1s[blk]; const float* B1 = b1s[blk];
        const float* W2 = W2s[blk]; const float* B2 = b2s[blk];

        // ---- GEMM1: h(64x64) = silu(x @ W1^T + b1), K=128 in 4 chunks of 32
        float acc[4][4] = {};
        #pragma unroll 1
        for (int k0 = 0; k0 < 128; k0 += 32) {
            #pragma unroll
            for (int it = 0; it < 2; ++it) {
                int task = it * 256 + tid;          // 512 float4 tasks
                int n    = task >> 3;               // 0..63
                int kl   = (task & 7) * 4;          // 0..28
                float4 vv = *(const float4*)(W1 + (size_t)n * 128 + k0 + kl);
                w_sh[kl + 0][n] = vv.x; w_sh[kl + 1][n] = vv.y;
                w_sh[kl + 2][n] = vv.z; w_sh[kl + 3][n] = vv.w;
            }
            __syncthreads();
            #pragma unroll
            for (int kk = 0; kk < 32; ++kk) {
                float a0 = x_sh[tm4 + 0][k0 + kk], a1 = x_sh[tm4 + 1][k0 + kk];
                float a2 = x_sh[tm4 + 2][k0 + kk], a3 = x_sh[tm4 + 3][k0 + kk];
                float4 b4 = *(const float4*)&w_sh[kk][tn4];
                float bv[4] = {b4.x, b4.y, b4.z, b4.w};
                #pragma unroll
                for (int j = 0; j < 4; ++j) {
                    acc[0][j] += a0 * bv[j]; acc[1][j] += a1 * bv[j];
                    acc[2][j] += a2 * bv[j]; acc[3][j] += a3 * bv[j];
                }
            }
            __syncthreads();
        }
        #pragma unroll
        for (int i = 0; i < 4; ++i)
            #pragma unroll
            for (int j = 0; j < 4; ++j) {
                float a = acc[i][j] + B1[tn4 + j];
                h_sh[tm4 + i][tn4 + j] = a / (1.f + __expf(-a));
            }

        // ---- GEMM2: x(64x128) += h @ W2^T + b2, two 64-col halves, K=64 in 2 chunks
        #pragma unroll 1
        for (int half = 0; half < 2; ++half) {
            float acc2[4][4] = {};
            #pragma unroll 1
            for (int k0 = 0; k0 < 64; k0 += 32) {
                #pragma unroll
                for (int it = 0; it < 2; ++it) {
                    int task = it * 256 + tid;
                    int n    = task >> 3;
                    int kl   = (task & 7) * 4;
                    float4 vv = *(const float4*)(W2 + (size_t)(half * 64 + n) * 64 + k0 + kl);
                    w_sh[kl + 0][n] = vv.x; w_sh[kl + 1][n] = vv.y;
                    w_sh[kl + 2][n] = vv.z; w_sh[kl + 3][n] = vv.w;
                }
                __syncthreads();
                #pragma unroll
                for (int kk = 0; kk < 32; ++kk) {
                    float a0 = h_sh[tm4 + 0][k0 + kk], a1 = h_sh[tm4 + 1][k0 + kk];
                    float a2 = h_sh[tm4 + 2][k0 + kk], a3 = h_sh[tm4 + 3][k0 + kk];
                    float4 b4 = *(const float4*)&w_sh[kk][tn4];
                    float bv[4] = {b4.x, b4.y, b4.z, b4.w};
                    #pragma unroll
                    for (int j = 0; j < 4; ++j) {
                        acc2[0][j] += a0 * bv[j]; acc2[1][j] += a1 * bv[j];
                        acc2[2][j] += a2 * bv[j]; acc2[3][j] += a3 * bv[j];
                    }
                }
                __syncthreads();
            }
            #pragma unroll
            for (int i = 0; i < 4; ++i)
                #pragma unroll
                for (int j = 0; j < 4; ++j)
                    x_sh[tm4 + i][half * 64 + tn4 + j] += acc2[i][j] + B2[half * 64 + tn4 + j];
            __syncthreads();   // x_sh/w_sh reuse boundary
        }
    }

    // ---- phase 5: out = INV_SQRT_2 * (nbr_fea + x)
    {
        int m = tid >> 2;
        int q = tid & 3;
        int e = row0 + m;
        if (e < N_EDGES) {
            const float4* nf = (const float4*)(nbr_fea + (size_t)e * NF + q * 32);
            float4* dst      = (float4*)(out + (size_t)e * NF + q * 32);
            #pragma unroll
            for (int t = 0; t < 8; ++t) {
                float4 f = nf[t];
                int col = q * 32 + 4 * t;
                dst[t] = make_float4(
                    INV_SQRT_2 * (f.x + x_sh[m][col + 0]),
                    INV_SQRT_2 * (f.y + x_sh[m][col + 1]),
                    INV_SQRT_2 * (f.z + x_sh[m][col + 2]),
                    INV_SQRT_2 * (f.w + x_sh[m][col + 3]));
            }
        }
    }
}

// ---------------- workspace layout (bytes) ----------------
//   [0,              524288)   segSum   (512*256 f32)  -> mean after finalize
//   [524288,        1048576)   segSumSq (512*256 f32)  -> scale after finalize
//   [1048576,      52248576)   s_acc    (100000*128 f32)
//   [52248576,     52648576)   c_acc    (100000 f32)
//   --- everything above zeroed each launch ---
//   [52648576,     52652672)   seg_start (513 i32, padded)
//   [52652672,    257452672)   h (400000*256 bf16)

extern "C" void kernel_launch(void* const* d_in, const int* in_sizes, int n_in,
                              void* d_out, int out_size, void* d_ws, size_t ws_size,
                              hipStream_t stream) {
    const float* nbr_fea       = (const float*)d_in[0];
    const float* angle_fea     = (const float*)d_in[1];
    const int*   angle_nbr_idx = (const int*)d_in[2];
    const int*   cai           = (const int*)d_in[4];
    const float* W_full        = (const float*)d_in[5];
    const float* W_mask        = (const float*)d_in[6];
    const float* cn_gamma      = (const float*)d_in[7];
    const float* cn_beta       = (const float*)d_in[8];
    const float* ln_core_g     = (const float*)d_in[9];
    const float* ln_core_b     = (const float*)d_in[10];
    const float* ln2_g         = (const float*)d_in[11];
    const float* ln2_b         = (const float*)d_in[12];
    const float* W1a           = (const float*)d_in[13];
    const float* b1a           = (const float*)d_in[14];
    const float* W2a           = (const float*)d_in[15];
    const float* b2a           = (const float*)d_in[16];
    const float* W1b           = (const float*)d_in[17];
    const float* b1b           = (const float*)d_in[18];
    const float* W2b           = (const float*)d_in[19];
    const float* b2b           = (const float*)d_in[20];
    float* out = (float*)d_out;

    char* ws = (char*)d_ws;
    float* segSum    = (float*)(ws + 0);
    float* segSumSq  = (float*)(ws + 524288);
    float* s_acc     = (float*)(ws + 1048576);
    float* c_acc     = (float*)(ws + 52248576);
    int*   seg_start = (int*)  (ws + 52648576);
    __hip_bfloat16* h = (__hip_bfloat16*)(ws + 52652672);

    hipMemsetAsync(ws, 0, 52648576, stream);

    seg_bounds<<<3, 256, 0, stream>>>(cai, seg_start);
    gemm_gather<<<dim3(N_ANGLES / BM, TWOF / BN), 256, 0, stream>>>(
        angle_fea, nbr_fea, angle_nbr_idx, W_full, h);
    seg_stats<<<dim3(N_CRYST, 4), 256, 0, stream>>>(h, seg_start, segSum, segSumSq);
    seg_finalize<<<N_CRYST, 256, 0, stream>>>(seg_start, segSum, segSumSq);
    angle_msg<<<N_ANGLES / 4, 256, 0, stream>>>(
        h, cai, angle_nbr_idx, segSum, segSumSq,
        cn_gamma, cn_beta, ln_core_g, ln_core_b, W_mask, s_acc, c_acc);
    edge_mlp<<<(N_EDGES + MT - 1) / MT, 256, 0, stream>>>(
        s_acc, c_acc, nbr_fea, ln2_g, ln2_b,
        W1a, b1a, W2a, b2a, W1b, b1b, W2b, b2b, out);
}

// Round 3
// 919.360 us; speedup vs baseline: 3.2500x; 1.8149x over previous
//
#include <hip/hip_runtime.h>
#include <hip/hip_bf16.h>
#include <cstdint>
#include <cstddef>

// Problem constants
#define NF 128        // F
#define N_EDGES 100000
#define N_ANGLES 400000
#define N_CRYST 512
#define KDIM 320      // 2F + A
#define TWOF 256
#define EPS_LN 1e-5f
#define INV_SQRT_2 0.70710678118654752440f

typedef short short8 __attribute__((ext_vector_type(8)));
typedef float floatx4 __attribute__((ext_vector_type(4)));

// ---------------- helpers ----------------
__device__ inline unsigned short f2bf(float x) {
    __hip_bfloat16 b = __float2bfloat16(x);
    return *reinterpret_cast<unsigned short*>(&b);
}
__device__ inline float bf2f(__hip_bfloat16 b) { return __bfloat162float(b); }

__device__ inline uint4 cvt8(float4 a, float4 b) {
    __hip_bfloat162 p0 = __float22bfloat162_rn(make_float2(a.x, a.y));
    __hip_bfloat162 p1 = __float22bfloat162_rn(make_float2(a.z, a.w));
    __hip_bfloat162 p2 = __float22bfloat162_rn(make_float2(b.x, b.y));
    __hip_bfloat162 p3 = __float22bfloat162_rn(make_float2(b.z, b.w));
    uint4 r;
    r.x = *reinterpret_cast<unsigned int*>(&p0);
    r.y = *reinterpret_cast<unsigned int*>(&p1);
    r.z = *reinterpret_cast<unsigned int*>(&p2);
    r.w = *reinterpret_cast<unsigned int*>(&p3);
    return r;
}

// ---------------- kernel 1: segment boundaries (sorted crystal_angle_index) ----------------
__global__ void seg_bounds(const int* __restrict__ seg, int* __restrict__ seg_start) {
    int s = blockIdx.x * blockDim.x + threadIdx.x;
    if (s > N_CRYST) return;
    if (s == N_CRYST) { seg_start[N_CRYST] = N_ANGLES; return; }
    int lo = 0, hi = N_ANGLES;
    while (lo < hi) { int mid = (lo + hi) >> 1; if (seg[mid] < s) lo = mid + 1; else hi = mid; }
    seg_start[s] = lo;
}

// ---------------- kernel 2: fused gather + GEMM via bf16 MFMA ----------------
// h = total @ W_full^T, computed transposed: D[n][m] = sum_k W[n][k]*total[m][k]
// Tile: 128 rows (m) x 128 cols (n), BK=32, 10 K-iters (fully unrolled so the
// gather region select [angle | nbr0 | nbr1] is compile-time per iter).
// LDS XOR-swizzle (chunk ^ (row>>1)&3) -> fragment ds_read_b128 2-way max (free).
__global__ __launch_bounds__(256) void gemm_gather_mfma(
    const float* __restrict__ angle_fea,      // N_ANGLES x 64
    const float* __restrict__ nbr_fea,        // N_EDGES x 128
    const int*   __restrict__ angle_nbr_idx,  // N_ANGLES x 2
    const float* __restrict__ W_full,         // 256 x 320 (row-major)
    __hip_bfloat16* __restrict__ hout)        // N_ANGLES x 256
{
    __shared__ uint4 X_lds[512];   // 128 rows x 32 k bf16 (8 KB), swizzled
    __shared__ uint4 W_lds[512];   // 128 n    x 32 k bf16 (8 KB), swizzled

    const int tid  = threadIdx.x;
    const int row0 = blockIdx.x * 128;    // 3125 blocks, exact
    const int col0 = blockIdx.y * 128;    // 2 blocks

    // Each thread stages 2 chunks (16B bf16 = 8 k-elems) per matrix per K-iter.
    // Chunk slot tau = it*256+tid; row m = tau>>2; logical k-chunk = (tau&3) ^ g(m).
    int mrow[2], koff[2], p0r[2], p1r[2];
    #pragma unroll
    for (int it = 0; it < 2; ++it) {
        int tau = it * 256 + tid;
        int m   = tau >> 2;
        mrow[it] = m;
        koff[it] = (((tau & 3) ^ ((m >> 1) & 3))) * 8;   // element offset in [0,32)
        p0r[it] = angle_nbr_idx[(size_t)(row0 + m) * 2 + 0];
        p1r[it] = angle_nbr_idx[(size_t)(row0 + m) * 2 + 1];
    }

    const int wave = tid >> 6, lane = tid & 63;
    const int wrow = (wave & 1) * 64;      // m-quadrant
    const int wcol = (wave >> 1) * 64;     // n-quadrant
    const int rl   = lane & 15, kgrp = lane >> 4;
    const int fragoff = ((kgrp ^ ((rl >> 1) & 3)) * 16);  // swizzled byte offset
    const char* Xb = (const char*)X_lds;
    const char* Wb = (const char*)W_lds;

    floatx4 acc[4][4];
    #pragma unroll
    for (int i = 0; i < 4; ++i)
        #pragma unroll
        for (int j = 0; j < 4; ++j)
            acc[i][j] = (floatx4){0.f, 0.f, 0.f, 0.f};

    #pragma unroll
    for (int kiter = 0; kiter < 10; ++kiter) {
        const int kbase = kiter * 32;
        // ---- stage X (gathered rows), bf16-converted
        #pragma unroll
        for (int it = 0; it < 2; ++it) {
            int m = mrow[it];
            int k = koff[it];
            const float* src;
            if (kbase < 64)       src = angle_fea + (size_t)(row0 + m) * 64 + kbase + k;
            else if (kbase < 192) src = nbr_fea + (size_t)p0r[it] * 128 + (kbase - 64) + k;
            else                  src = nbr_fea + (size_t)p1r[it] * 128 + (kbase - 192) + k;
            float4 a = ((const float4*)src)[0];
            float4 b = ((const float4*)src)[1];
            X_lds[it * 256 + tid] = cvt8(a, b);
        }
        // ---- stage W
        #pragma unroll
        for (int it = 0; it < 2; ++it) {
            int n = mrow[it];
            int k = koff[it];
            const float* src = W_full + (size_t)(col0 + n) * KDIM + kbase + k;
            float4 a = ((const float4*)src)[0];
            float4 b = ((const float4*)src)[1];
            W_lds[it * 256 + tid] = cvt8(a, b);
        }
        __syncthreads();
        // ---- fragments + MFMA
        short8 wf[4], xf[4];
        #pragma unroll
        for (int i = 0; i < 4; ++i)
            wf[i] = *(const short8*)(Wb + (size_t)(wcol + i * 16 + rl) * 64 + fragoff);
        #pragma unroll
        for (int j = 0; j < 4; ++j)
            xf[j] = *(const short8*)(Xb + (size_t)(wrow + j * 16 + rl) * 64 + fragoff);
        #pragma unroll
        for (int i = 0; i < 4; ++i)
            #pragma unroll
            for (int j = 0; j < 4; ++j)
                acc[i][j] = __builtin_amdgcn_mfma_f32_16x16x32_bf16(wf[i], xf[j], acc[i][j], 0, 0, 0);
        __syncthreads();
    }

    // ---- epilogue: D[n][m] -> h[m][n]; lane holds 4 consecutive n per (i,j)
    // h row = row0 + wrow + j*16 + rl; h cols = col0 + wcol + i*16 + kgrp*4 + [0,4)
    unsigned short* hp = reinterpret_cast<unsigned short*>(hout);
    #pragma unroll
    for (int j = 0; j < 4; ++j) {
        size_t r = (size_t)(row0 + wrow + j * 16 + rl);
        #pragma unroll
        for (int i = 0; i < 4; ++i) {
            int c = col0 + wcol + i * 16 + kgrp * 4;
            floatx4 v = acc[i][j];
            uint2 pk;
            pk.x = (unsigned int)f2bf(v[0]) | ((unsigned int)f2bf(v[1]) << 16);
            pk.y = (unsigned int)f2bf(v[2]) | ((unsigned int)f2bf(v[3]) << 16);
            *reinterpret_cast<uint2*>(hp + r * TWOF + c) = pk;
        }
    }
}

// ---------------- kernel 3: per-segment sum / sumsq ----------------
__global__ __launch_bounds__(256) void seg_stats(
    const __hip_bfloat16* __restrict__ h,
    const int* __restrict__ seg_start,
    float* __restrict__ segSum, float* __restrict__ segSumSq)
{
    int seg   = blockIdx.x;
    int split = blockIdx.y;  // 0..3
    int start = seg_start[seg], end = seg_start[seg + 1];
    int n = end - start;
    if (n <= 0) return;
    int per = (n + 3) >> 2;
    int r0 = start + split * per;
    int r1 = min(r0 + per, end);
    if (r0 >= r1) return;
    int j = threadIdx.x;
    float sum = 0.f, ss = 0.f;
    for (int r = r0; r < r1; ++r) {
        float v = bf2f(h[(size_t)r * TWOF + j]);
        sum += v; ss += v * v;
    }
    atomicAdd(&segSum[seg * TWOF + j], sum);
    atomicAdd(&segSumSq[seg * TWOF + j], ss);
}

// ---------------- kernel 4: finalize mean / rsqrt(var+eps) in place ----------------
__global__ __launch_bounds__(256) void seg_finalize(
    const int* __restrict__ seg_start,
    float* __restrict__ segSum, float* __restrict__ segSumSq)
{
    int seg = blockIdx.x;
    int j = threadIdx.x;
    float cnt = (float)max(seg_start[seg + 1] - seg_start[seg], 1);
    float inv = 1.0f / cnt;
    float mean = segSum[seg * TWOF + j] * inv;
    float var  = segSumSq[seg * TWOF + j] * inv - mean * mean;
    segSum[seg * TWOF + j]   = mean;
    segSumSq[seg * TWOF + j] = rsqrtf(var + EPS_LN);
}

// ---------------- kernel 5: per-angle normalize + LN(core) + gate + scatter ----------------
__global__ __launch_bounds__(256) void angle_msg(
    const __hip_bfloat16* __restrict__ h,
    const int* __restrict__ seg_idx,
    const int* __restrict__ angle_nbr_idx,
    const float* __restrict__ segMean, const float* __restrict__ segScale,
    const float* __restrict__ cn_gamma, const float* __restrict__ cn_beta,
    const float* __restrict__ ln_g, const float* __restrict__ ln_b,
    const float* __restrict__ w_mask,
    float* __restrict__ s_acc, float* __restrict__ c_acc)
{
    int row  = blockIdx.x * 4 + (threadIdx.x >> 6);
    int lane = threadIdx.x & 63;
    int seg  = seg_idx[row];
    int src  = angle_nbr_idx[(size_t)row * 2];

    const __hip_bfloat16* hr = h + (size_t)row * TWOF;
    float y[4];
    #pragma unroll
    for (int q = 0; q < 4; ++q) {
        int col = lane + q * 64;
        float v = bf2f(hr[col]);
        float m = segMean[seg * TWOF + col], sc = segScale[seg * TWOF + col];
        y[q] = (v - m) * sc * cn_gamma[col] + cn_beta[col];
    }
    float sum = y[0] + y[1], ssq = y[0] * y[0] + y[1] * y[1];
    #pragma unroll
    for (int o = 32; o > 0; o >>= 1) { sum += __shfl_xor(sum, o, 64); ssq += __shfl_xor(ssq, o, 64); }
    float mu  = sum * (1.f / 128.f);
    float var = ssq * (1.f / 128.f) - mu * mu;
    float rs  = rsqrtf(var + EPS_LN);
    float ln0 = (y[0] - mu) * rs * ln_g[lane]      + ln_b[lane];
    float ln1 = (y[1] - mu) * rs * ln_g[lane + 64] + ln_b[lane + 64];
    float si0 = ln0 / (1.f + __expf(-ln0));
    float si1 = ln1 / (1.f + __expf(-ln1));
    float gp = y[2] * w_mask[lane] + y[3] * w_mask[lane + 64];
    #pragma unroll
    for (int o = 32; o > 0; o >>= 1) gp += __shfl_xor(gp, o, 64);
    float gate = 1.f / (1.f + __expf(-gp));

    atomicAdd(&s_acc[(size_t)src * NF + lane],      gate * si0);
    atomicAdd(&s_acc[(size_t)src * NF + lane + 64], gate * si1);
    if (lane == 0) atomicAdd(&c_acc[src], 1.0f);
}

// ---------------- kernel 6: edge MLP as blocked GEMM ----------------
#define MT 64
__global__ __launch_bounds__(256) void edge_mlp(
    const float* __restrict__ s_acc, const float* __restrict__ c_acc,
    const float* __restrict__ nbr_fea,
    const float* __restrict__ ln2_g, const float* __restrict__ ln2_b,
    const float* __restrict__ W1a, const float* __restrict__ b1a,
    const float* __restrict__ W2a, const float* __restrict__ b2a,
    const float* __restrict__ W1b, const float* __restrict__ b1b,
    const float* __restrict__ W2b, const float* __restrict__ b2b,
    float* __restrict__ out)
{
    __shared__ float x_sh[MT][132];
    __shared__ float h_sh[MT][68];
    __shared__ float w_sh[32][68];

    const int tid  = threadIdx.x;
    const int row0 = blockIdx.x * MT;
    const int ty = tid >> 4, tx = tid & 15;
    const int tm4 = ty * 4, tn4 = tx * 4;

    {
        int m = tid >> 2;
        int q = tid & 3;
        int e = min(row0 + m, N_EDGES - 1);
        float inv = 1.f / fmaxf(c_acc[e], 1.f);
        const float4* src = (const float4*)(s_acc + (size_t)e * NF + q * 32);
        float v[32];
        float sum = 0.f, ssq = 0.f;
        #pragma unroll
        for (int t = 0; t < 8; ++t) {
            float4 f = src[t];
            v[4*t+0] = f.x * inv; v[4*t+1] = f.y * inv; v[4*t+2] = f.z * inv; v[4*t+3] = f.w * inv;
        }
        #pragma unroll
        for (int i = 0; i < 32; ++i) { sum += v[i]; ssq += v[i] * v[i]; }
        sum += __shfl_xor(sum, 1, 64); ssq += __shfl_xor(ssq, 1, 64);
        sum += __shfl_xor(sum, 2, 64); ssq += __shfl_xor(ssq, 2, 64);
        float mu  = sum * (1.f / 128.f);
        float var = ssq * (1.f / 128.f) - mu * mu;
        float rs  = rsqrtf(var + EPS_LN);
        #pragma unroll
        for (int i = 0; i < 32; ++i) {
            int col = q * 32 + i;
            x_sh[m][col] = (v[i] - mu) * rs * ln2_g[col] + ln2_b[col];
        }
    }
    __syncthreads();

    const float* W1s[2] = {W1a, W1b};
    const float* b1s[2] = {b1a, b1b};
    const float* W2s[2] = {W2a, W2b};
    const float* b2s[2] = {b2a, b2b};

    #pragma unroll 1
    for (int blk = 0; blk < 2; ++blk) {
        const float* W1 = W1s[blk]; const float* B1 = b1s[blk];
        const float* W2 = W2s[blk]; const float* B2 = b2s[blk];

        float acc[4][4] = {};
        #pragma unroll 1
        for (int k0 = 0; k0 < 128; k0 += 32) {
            #pragma unroll
            for (int it = 0; it < 2; ++it) {
                int task = it * 256 + tid;
                int n    = task >> 3;
                int kl   = (task & 7) * 4;
                float4 vv = *(const float4*)(W1 + (size_t)n * 128 + k0 + kl);
                w_sh[kl + 0][n] = vv.x; w_sh[kl + 1][n] = vv.y;
                w_sh[kl + 2][n] = vv.z; w_sh[kl + 3][n] = vv.w;
            }
            __syncthreads();
            #pragma unroll
            for (int kk = 0; kk < 32; ++kk) {
                float a0 = x_sh[tm4 + 0][k0 + kk], a1 = x_sh[tm4 + 1][k0 + kk];
                float a2 = x_sh[tm4 + 2][k0 + kk], a3 = x_sh[tm4 + 3][k0 + kk];
                float4 b4 = *(const float4*)&w_sh[kk][tn4];
                float bv[4] = {b4.x, b4.y, b4.z, b4.w};
                #pragma unroll
                for (int j = 0; j < 4; ++j) {
                    acc[0][j] += a0 * bv[j]; acc[1][j] += a1 * bv[j];
                    acc[2][j] += a2 * bv[j]; acc[3][j] += a3 * bv[j];
                }
            }
            __syncthreads();
        }
        #pragma unroll
        for (int i = 0; i < 4; ++i)
            #pragma unroll
            for (int j = 0; j < 4; ++j) {
                float a = acc[i][j] + B1[tn4 + j];
                h_sh[tm4 + i][tn4 + j] = a / (1.f + __expf(-a));
            }

        #pragma unroll 1
        for (int half = 0; half < 2; ++half) {
            float acc2[4][4] = {};
            #pragma unroll 1
            for (int k0 = 0; k0 < 64; k0 += 32) {
                #pragma unroll
                for (int it = 0; it < 2; ++it) {
                    int task = it * 256 + tid;
                    int n    = task >> 3;
                    int kl   = (task & 7) * 4;
                    float4 vv = *(const float4*)(W2 + (size_t)(half * 64 + n) * 64 + k0 + kl);
                    w_sh[kl + 0][n] = vv.x; w_sh[kl + 1][n] = vv.y;
                    w_sh[kl + 2][n] = vv.z; w_sh[kl + 3][n] = vv.w;
                }
                __syncthreads();
                #pragma unroll
                for (int kk = 0; kk < 32; ++kk) {
                    float a0 = h_sh[tm4 + 0][k0 + kk], a1 = h_sh[tm4 + 1][k0 + kk];
                    float a2 = h_sh[tm4 + 2][k0 + kk], a3 = h_sh[tm4 + 3][k0 + kk];
                    float4 b4 = *(const float4*)&w_sh[kk][tn4];
                    float bv[4] = {b4.x, b4.y, b4.z, b4.w};
                    #pragma unroll
                    for (int j = 0; j < 4; ++j) {
                        acc2[0][j] += a0 * bv[j]; acc2[1][j] += a1 * bv[j];
                        acc2[2][j] += a2 * bv[j]; acc2[3][j] += a3 * bv[j];
                    }
                }
                __syncthreads();
            }
            #pragma unroll
            for (int i = 0; i < 4; ++i)
                #pragma unroll
                for (int j = 0; j < 4; ++j)
                    x_sh[tm4 + i][half * 64 + tn4 + j] += acc2[i][j] + B2[half * 64 + tn4 + j];
            __syncthreads();
        }
    }

    {
        int m = tid >> 2;
        int q = tid & 3;
        int e = row0 + m;
        if (e < N_EDGES) {
            const float4* nf = (const float4*)(nbr_fea + (size_t)e * NF + q * 32);
            float4* dst      = (float4*)(out + (size_t)e * NF + q * 32);
            #pragma unroll
            for (int t = 0; t < 8; ++t) {
                float4 f = nf[t];
                int col = q * 32 + 4 * t;
                dst[t] = make_float4(
                    INV_SQRT_2 * (f.x + x_sh[m][col + 0]),
                    INV_SQRT_2 * (f.y + x_sh[m][col + 1]),
                    INV_SQRT_2 * (f.z + x_sh[m][col + 2]),
                    INV_SQRT_2 * (f.w + x_sh[m][col + 3]));
            }
        }
    }
}

// ---------------- workspace layout (bytes) ----------------
//   [0,              524288)   segSum   (512*256 f32)  -> mean after finalize
//   [524288,        1048576)   segSumSq (512*256 f32)  -> scale after finalize
//   [1048576,      52248576)   s_acc    (100000*128 f32)
//   [52248576,     52648576)   c_acc    (100000 f32)
//   --- everything above zeroed each launch ---
//   [52648576,     52652672)   seg_start (513 i32, padded)
//   [52652672,    257452672)   h (400000*256 bf16)

extern "C" void kernel_launch(void* const* d_in, const int* in_sizes, int n_in,
                              void* d_out, int out_size, void* d_ws, size_t ws_size,
                              hipStream_t stream) {
    const float* nbr_fea       = (const float*)d_in[0];
    const float* angle_fea     = (const float*)d_in[1];
    const int*   angle_nbr_idx = (const int*)d_in[2];
    const int*   cai           = (const int*)d_in[4];
    const float* W_full        = (const float*)d_in[5];
    const float* W_mask        = (const float*)d_in[6];
    const float* cn_gamma      = (const float*)d_in[7];
    const float* cn_beta       = (const float*)d_in[8];
    const float* ln_core_g     = (const float*)d_in[9];
    const float* ln_core_b     = (const float*)d_in[10];
    const float* ln2_g         = (const float*)d_in[11];
    const float* ln2_b         = (const float*)d_in[12];
    const float* W1a           = (const float*)d_in[13];
    const float* b1a           = (const float*)d_in[14];
    const float* W2a           = (const float*)d_in[15];
    const float* b2a           = (const float*)d_in[16];
    const float* W1b           = (const float*)d_in[17];
    const float* b1b           = (const float*)d_in[18];
    const float* W2b           = (const float*)d_in[19];
    const float* b2b           = (const float*)d_in[20];
    float* out = (float*)d_out;

    char* ws = (char*)d_ws;
    float* segSum    = (float*)(ws + 0);
    float* segSumSq  = (float*)(ws + 524288);
    float* s_acc     = (float*)(ws + 1048576);
    float* c_acc     = (float*)(ws + 52248576);
    int*   seg_start = (int*)  (ws + 52648576);
    __hip_bfloat16* h = (__hip_bfloat16*)(ws + 52652672);

    hipMemsetAsync(ws, 0, 52648576, stream);

    seg_bounds<<<3, 256, 0, stream>>>(cai, seg_start);
    gemm_gather_mfma<<<dim3(N_ANGLES / 128, 2), 256, 0, stream>>>(
        angle_fea, nbr_fea, angle_nbr_idx, W_full, h);
    seg_stats<<<dim3(N_CRYST, 4), 256, 0, stream>>>(h, seg_start, segSum, segSumSq);
    seg_finalize<<<N_CRYST, 256, 0, stream>>>(seg_start, segSum, segSumSq);
    angle_msg<<<N_ANGLES / 4, 256, 0, stream>>>(
        h, cai, angle_nbr_idx, segSum, segSumSq,
        cn_gamma, cn_beta, ln_core_g, ln_core_b, W_mask, s_acc, c_acc);
    edge_mlp<<<(N_EDGES + MT - 1) / MT, 256, 0, stream>>>(
        s_acc, c_acc, nbr_fea, ln2_g, ln2_b,
        W1a, b1a, W2a, b2a, W1b, b1b, W2b, b2b, out);
}

// Round 4
// 689.674 us; speedup vs baseline: 4.3324x; 1.3330x over previous
//
#include <hip/hip_runtime.h>
#include <hip/hip_bf16.h>
#include <cstdint>
#include <cstddef>

// Problem constants
#define NF 128        // F
#define N_EDGES 100000
#define N_ANGLES 400000
#define N_CRYST 512
#define KDIM 320      // 2F + A
#define TWOF 256
#define EPS_LN 1e-5f
#define INV_SQRT_2 0.70710678118654752440f

typedef short short8 __attribute__((ext_vector_type(8)));
typedef float floatx4 __attribute__((ext_vector_type(4)));

// ---------------- helpers ----------------
__device__ inline unsigned short f2bf(float x) {
    __hip_bfloat16 b = __float2bfloat16(x);
    return *reinterpret_cast<unsigned short*>(&b);
}
__device__ inline float bf2f(__hip_bfloat16 b) { return __bfloat162float(b); }
__device__ inline float bfbits2f(unsigned short u) {
    unsigned int v = ((unsigned int)u) << 16;
    return __uint_as_float(v);
}

__device__ inline uint4 cvt8(float4 a, float4 b) {
    __hip_bfloat162 p0 = __float22bfloat162_rn(make_float2(a.x, a.y));
    __hip_bfloat162 p1 = __float22bfloat162_rn(make_float2(a.z, a.w));
    __hip_bfloat162 p2 = __float22bfloat162_rn(make_float2(b.x, b.y));
    __hip_bfloat162 p3 = __float22bfloat162_rn(make_float2(b.z, b.w));
    uint4 r;
    r.x = *reinterpret_cast<unsigned int*>(&p0);
    r.y = *reinterpret_cast<unsigned int*>(&p1);
    r.z = *reinterpret_cast<unsigned int*>(&p2);
    r.w = *reinterpret_cast<unsigned int*>(&p3);
    return r;
}

// ---------------- kernel 1: segment boundaries (sorted crystal_angle_index) ----------------
__global__ void seg_bounds(const int* __restrict__ seg, int* __restrict__ seg_start) {
    int s = blockIdx.x * blockDim.x + threadIdx.x;
    if (s > N_CRYST) return;
    if (s == N_CRYST) { seg_start[N_CRYST] = N_ANGLES; return; }
    int lo = 0, hi = N_ANGLES;
    while (lo < hi) { int mid = (lo + hi) >> 1; if (seg[mid] < s) lo = mid + 1; else hi = mid; }
    seg_start[s] = lo;
}

// ---------------- kernel 2: fused gather + GEMM via bf16 MFMA (v2) ----------------
// 128 rows x ALL 256 cols per block (gather once), 512 threads = 8 waves.
// Register prefetch: iter k+1's global loads issued before iter k's MFMA so the
// ~900-cyc random nbr gather overlaps compute instead of stalling at the barrier.
__global__ __launch_bounds__(512) void gemm_gather_mfma(
    const float* __restrict__ angle_fea,      // N_ANGLES x 64
    const float* __restrict__ nbr_fea,        // N_EDGES x 128
    const int*   __restrict__ angle_nbr_idx,  // N_ANGLES x 2
    const float* __restrict__ W_full,         // 256 x 320 (row-major)
    __hip_bfloat16* __restrict__ hout)        // N_ANGLES x 256
{
    __shared__ uint4 X_lds[512];    // 128 rows x 32 k bf16 (8 KB), swizzled
    __shared__ uint4 W_lds[1024];   // 256 n    x 32 k bf16 (16 KB), swizzled

    const int tid  = threadIdx.x;
    const int row0 = blockIdx.x * 128;    // 3125 blocks, exact

    // X staging: 512 chunks (16B bf16 = 8 k-elems), 1 per thread.
    const int xm = tid >> 2;
    const int xk = ((tid & 3) ^ ((xm >> 1) & 3)) * 8;
    const int p0 = angle_nbr_idx[(size_t)(row0 + xm) * 2 + 0];
    const int p1 = angle_nbr_idx[(size_t)(row0 + xm) * 2 + 1];
    // W staging: 1024 chunks, 2 per thread.
    int wn[2], wk[2];
    #pragma unroll
    for (int it = 0; it < 2; ++it) {
        int tau = it * 512 + tid;
        wn[it] = tau >> 2;
        wk[it] = ((tau & 3) ^ ((wn[it] >> 1) & 3)) * 8;
    }

    const int wave = tid >> 6, lane = tid & 63;
    const int wrow = (wave & 1) * 64;      // m-quadrant (2 of 128)
    const int wcol = (wave >> 1) * 64;     // n-quadrant (4 of 256)
    const int rl   = lane & 15, kgrp = lane >> 4;
    const int fragoff = (kgrp ^ ((rl >> 1) & 3)) * 16;  // swizzled byte offset
    const char* Xb = (const char*)X_lds;
    const char* Wb = (const char*)W_lds;

    floatx4 acc[4][4];
    #pragma unroll
    for (int i = 0; i < 4; ++i)
        #pragma unroll
        for (int j = 0; j < 4; ++j)
            acc[i][j] = (floatx4){0.f, 0.f, 0.f, 0.f};

    float4 xa, xb2, wa0, wb0, wa1, wb1;   // prefetch registers
    auto loadX = [&](int kbase, float4& a, float4& b) {
        const float* src;
        if (kbase < 64)       src = angle_fea + (size_t)(row0 + xm) * 64 + kbase + xk;
        else if (kbase < 192) src = nbr_fea + (size_t)p0 * 128 + (kbase - 64) + xk;
        else                  src = nbr_fea + (size_t)p1 * 128 + (kbase - 192) + xk;
        a = ((const float4*)src)[0];
        b = ((const float4*)src)[1];
    };
    auto loadW = [&](int kbase, int it, float4& a, float4& b) {
        const float* src = W_full + (size_t)wn[it] * KDIM + kbase + wk[it];
        a = ((const float4*)src)[0];
        b = ((const float4*)src)[1];
    };

    loadX(0, xa, xb2);
    loadW(0, 0, wa0, wb0);
    loadW(0, 1, wa1, wb1);

    #pragma unroll
    for (int kiter = 0; kiter < 10; ++kiter) {
        uint4 xc  = cvt8(xa, xb2);
        uint4 wc0 = cvt8(wa0, wb0);
        uint4 wc1 = cvt8(wa1, wb1);
        if (kiter > 0) __syncthreads();   // previous iter's frag reads complete
        X_lds[tid]       = xc;
        W_lds[tid]       = wc0;
        W_lds[512 + tid] = wc1;
        __syncthreads();
        if (kiter < 9) {                  // prefetch next iter (overlaps MFMA below)
            int nb = (kiter + 1) * 32;
            loadX(nb, xa, xb2);
            loadW(nb, 0, wa0, wb0);
            loadW(nb, 1, wa1, wb1);
        }
        short8 wf[4], xf[4];
        #pragma unroll
        for (int i = 0; i < 4; ++i)
            wf[i] = *(const short8*)(Wb + (size_t)(wcol + i * 16 + rl) * 64 + fragoff);
        #pragma unroll
        for (int j = 0; j < 4; ++j)
            xf[j] = *(const short8*)(Xb + (size_t)(wrow + j * 16 + rl) * 64 + fragoff);
        #pragma unroll
        for (int i = 0; i < 4; ++i)
            #pragma unroll
            for (int j = 0; j < 4; ++j)
                acc[i][j] = __builtin_amdgcn_mfma_f32_16x16x32_bf16(wf[i], xf[j], acc[i][j], 0, 0, 0);
    }

    // epilogue: D[n][m] -> h[m][n]; lane holds 4 consecutive n per (i,j)
    unsigned short* hp = reinterpret_cast<unsigned short*>(hout);
    #pragma unroll
    for (int j = 0; j < 4; ++j) {
        size_t r = (size_t)(row0 + wrow + j * 16 + rl);
        #pragma unroll
        for (int i = 0; i < 4; ++i) {
            int c = wcol + i * 16 + kgrp * 4;
            floatx4 v = acc[i][j];
            uint2 pk;
            pk.x = (unsigned int)f2bf(v[0]) | ((unsigned int)f2bf(v[1]) << 16);
            pk.y = (unsigned int)f2bf(v[2]) | ((unsigned int)f2bf(v[3]) << 16);
            *reinterpret_cast<uint2*>(hp + r * TWOF + c) = pk;
        }
    }
}

// ---------------- kernel 3: per-segment sum / sumsq (vectorized 16B/lane) ----------------
// 8 row-groups x 32 col-threads; each thread: 8 consecutive cols via uint4.
__global__ __launch_bounds__(256) void seg_stats(
    const __hip_bfloat16* __restrict__ h,
    const int* __restrict__ seg_start,
    float* __restrict__ segSum, float* __restrict__ segSumSq)
{
    __shared__ float redS[8][256];
    __shared__ float redQ[8][256];
    int seg   = blockIdx.x;
    int split = blockIdx.y;  // 0..3
    int start = seg_start[seg], end = seg_start[seg + 1];
    int n = end - start;
    int g = threadIdx.x >> 5, t = threadIdx.x & 31;
    float s[8] = {0.f,0.f,0.f,0.f,0.f,0.f,0.f,0.f};
    float q[8] = {0.f,0.f,0.f,0.f,0.f,0.f,0.f,0.f};
    if (n > 0) {
        int per = (n + 3) >> 2;
        int r0 = start + split * per;
        int r1 = min(r0 + per, end);
        const unsigned short* hp = (const unsigned short*)h;
        for (int r = r0 + g; r < r1; r += 8) {
            uint4 v = *(const uint4*)(hp + (size_t)r * TWOF + t * 8);
            unsigned int d[4] = {v.x, v.y, v.z, v.w};
            #pragma unroll
            for (int i = 0; i < 4; ++i) {
                float lo = __uint_as_float(d[i] << 16);
                float hi = __uint_as_float(d[i] & 0xffff0000u);
                s[2*i]   += lo; q[2*i]   += lo * lo;
                s[2*i+1] += hi; q[2*i+1] += hi * hi;
            }
        }
    }
    #pragma unroll
    for (int i = 0; i < 8; ++i) { redS[g][t * 8 + i] = s[i]; redQ[g][t * 8 + i] = q[i]; }
    __syncthreads();
    if (n > 0) {
        int col = threadIdx.x;
        float S = 0.f, Q = 0.f;
        #pragma unroll
        for (int gg = 0; gg < 8; ++gg) { S += redS[gg][col]; Q += redQ[gg][col]; }
        atomicAdd(&segSum[seg * TWOF + col], S);
        atomicAdd(&segSumSq[seg * TWOF + col], Q);
    }
}

// ---------------- kernel 4: finalize mean / rsqrt(var+eps) in place ----------------
__global__ __launch_bounds__(256) void seg_finalize(
    const int* __restrict__ seg_start,
    float* __restrict__ segSum, float* __restrict__ segSumSq)
{
    int seg = blockIdx.x;
    int j = threadIdx.x;
    float cnt = (float)max(seg_start[seg + 1] - seg_start[seg], 1);
    float inv = 1.0f / cnt;
    float mean = segSum[seg * TWOF + j] * inv;
    float var  = segSumSq[seg * TWOF + j] * inv - mean * mean;
    segSum[seg * TWOF + j]   = mean;
    segSumSq[seg * TWOF + j] = rsqrtf(var + EPS_LN);
}

// ---------------- kernel 5: per-angle normalize + LN(core) + gate + scatter ----------------
__global__ __launch_bounds__(256) void angle_msg(
    const __hip_bfloat16* __restrict__ h,
    const int* __restrict__ seg_idx,
    const int* __restrict__ angle_nbr_idx,
    const float* __restrict__ segMean, const float* __restrict__ segScale,
    const float* __restrict__ cn_gamma, const float* __restrict__ cn_beta,
    const float* __restrict__ ln_g, const float* __restrict__ ln_b,
    const float* __restrict__ w_mask,
    float* __restrict__ s_acc, float* __restrict__ c_acc)
{
    int row  = blockIdx.x * 4 + (threadIdx.x >> 6);
    int lane = threadIdx.x & 63;
    int seg  = seg_idx[row];
    int src  = angle_nbr_idx[(size_t)row * 2];

    const __hip_bfloat16* hr = h + (size_t)row * TWOF;
    float y[4];
    #pragma unroll
    for (int qq = 0; qq < 4; ++qq) {
        int col = lane + qq * 64;
        float v = bf2f(hr[col]);
        float m = segMean[seg * TWOF + col], sc = segScale[seg * TWOF + col];
        y[qq] = (v - m) * sc * cn_gamma[col] + cn_beta[col];
    }
    float sum = y[0] + y[1], ssq = y[0] * y[0] + y[1] * y[1];
    #pragma unroll
    for (int o = 32; o > 0; o >>= 1) { sum += __shfl_xor(sum, o, 64); ssq += __shfl_xor(ssq, o, 64); }
    float mu  = sum * (1.f / 128.f);
    float var = ssq * (1.f / 128.f) - mu * mu;
    float rs  = rsqrtf(var + EPS_LN);
    float ln0 = (y[0] - mu) * rs * ln_g[lane]      + ln_b[lane];
    float ln1 = (y[1] - mu) * rs * ln_g[lane + 64] + ln_b[lane + 64];
    float si0 = ln0 / (1.f + __expf(-ln0));
    float si1 = ln1 / (1.f + __expf(-ln1));
    float gp = y[2] * w_mask[lane] + y[3] * w_mask[lane + 64];
    #pragma unroll
    for (int o = 32; o > 0; o >>= 1) gp += __shfl_xor(gp, o, 64);
    float gate = 1.f / (1.f + __expf(-gp));

    atomicAdd(&s_acc[(size_t)src * NF + lane],      gate * si0);
    atomicAdd(&s_acc[(size_t)src * NF + lane + 64], gate * si1);
    if (lane == 0) atomicAdd(&c_acc[src], 1.0f);
}

// ---------------- kernel 6: edge MLP via bf16 MFMA ----------------
// 64 edges/block, 256 threads (4 waves). All tensors bf16 in LDS, K-major,
// padded strides (136/72 elems -> 2-way banks = free). Wave w owns edge rows
// w*16..w*16+15 end-to-end (xb/h1 wave-local; only shared W buffer is barriered).
#define MT 64
#define XBS 136
#define H1S 72
#define W1S 136
#define W2S 72
__global__ __launch_bounds__(256) void edge_mlp_mfma(
    const float* __restrict__ s_acc, const float* __restrict__ c_acc,
    const float* __restrict__ nbr_fea,
    const float* __restrict__ ln2_g, const float* __restrict__ ln2_b,
    const float* __restrict__ W1a, const float* __restrict__ b1a,
    const float* __restrict__ W2a, const float* __restrict__ b2a,
    const float* __restrict__ W1b, const float* __restrict__ b1b,
    const float* __restrict__ W2b, const float* __restrict__ b2b,
    float* __restrict__ out)
{
    __shared__ unsigned short xb[MT * XBS];    // x (64x128 bf16), running value
    __shared__ unsigned short h1[MT * H1S];    // hidden (64x64 bf16)
    __shared__ unsigned short wl[128 * W2S];   // shared weight buffer (max of W1/W2)

    const int tid  = threadIdx.x;
    const int row0 = blockIdx.x * MT;
    const int w    = tid >> 6, lane = tid & 63;
    const int rl   = lane & 15, kgrp = lane >> 4;

    // ---- phase 0: nbr_sumed -> LN2 -> xb (bf16). 4 threads/edge, 32 feats each.
    {
        int m = tid >> 2;
        int q = tid & 3;
        int e = min(row0 + m, N_EDGES - 1);
        float inv = 1.f / fmaxf(c_acc[e], 1.f);
        const float4* src = (const float4*)(s_acc + (size_t)e * NF + q * 32);
        float v[32];
        float sum = 0.f, ssq = 0.f;
        #pragma unroll
        for (int t = 0; t < 8; ++t) {
            float4 f = src[t];
            v[4*t+0] = f.x * inv; v[4*t+1] = f.y * inv; v[4*t+2] = f.z * inv; v[4*t+3] = f.w * inv;
        }
        #pragma unroll
        for (int i = 0; i < 32; ++i) { sum += v[i]; ssq += v[i] * v[i]; }
        sum += __shfl_xor(sum, 1, 64); ssq += __shfl_xor(ssq, 1, 64);
        sum += __shfl_xor(sum, 2, 64); ssq += __shfl_xor(ssq, 2, 64);
        float mu  = sum * (1.f / 128.f);
        float var = ssq * (1.f / 128.f) - mu * mu;
        float rs  = rsqrtf(var + EPS_LN);
        #pragma unroll
        for (int i = 0; i < 32; ++i) {
            int col = q * 32 + i;
            v[i] = (v[i] - mu) * rs * ln2_g[col] + ln2_b[col];
        }
        #pragma unroll
        for (int t = 0; t < 4; ++t) {
            float4 a = make_float4(v[8*t+0], v[8*t+1], v[8*t+2], v[8*t+3]);
            float4 b = make_float4(v[8*t+4], v[8*t+5], v[8*t+6], v[8*t+7]);
            *(uint4*)&xb[m * XBS + q * 32 + t * 8] = cvt8(a, b);
        }
    }

    const float* W1s[2] = {W1a, W1b};
    const float* B1s[2] = {b1a, b1b};
    const float* W2s[2] = {W2a, W2b};
    const float* B2s[2] = {b2a, b2b};

    #pragma unroll 1
    for (int blk = 0; blk < 2; ++blk) {
        const float* W1 = W1s[blk]; const float* B1 = B1s[blk];
        const float* W2 = W2s[blk]; const float* B2 = B2s[blk];

        // ---- stage W1 (64 x 128) into wl, bf16
        __syncthreads();   // wl free (and phase-0 xb globally visible on blk 0)
        #pragma unroll
        for (int c = tid; c < 1024; c += 256) {
            int nn = c >> 4, kc = c & 15;
            const float* src = W1 + (size_t)nn * 128 + kc * 8;
            *(uint4*)&wl[nn * W1S + kc * 8] =
                cvt8(((const float4*)src)[0], ((const float4*)src)[1]);
        }
        __syncthreads();

        // ---- GEMM1: D1[n=64][m=16/wave] = sum_k W1[n][k] x[m][k], K=128
        short8 xf[4];
        #pragma unroll
        for (int ks = 0; ks < 4; ++ks)
            xf[ks] = *(const short8*)&xb[(w * 16 + rl) * XBS + ks * 32 + kgrp * 8];
        floatx4 a1[4];
        #pragma unroll
        for (int i = 0; i < 4; ++i) {
            a1[i] = (floatx4){0.f, 0.f, 0.f, 0.f};
            #pragma unroll
            for (int ks = 0; ks < 4; ++ks) {
                short8 wf = *(const short8*)&wl[(i * 16 + rl) * W1S + ks * 32 + kgrp * 8];
                a1[i] = __builtin_amdgcn_mfma_f32_16x16x32_bf16(wf, xf[ks], a1[i], 0, 0, 0);
            }
        }
        // silu + bias -> h1[m][n]  (lane: m = w*16+rl, n = i*16 + kgrp*4 + reg)
        #pragma unroll
        for (int i = 0; i < 4; ++i) {
            int nb = i * 16 + kgrp * 4;
            float s0 = a1[i][0] + B1[nb + 0];
            float s1 = a1[i][1] + B1[nb + 1];
            float s2 = a1[i][2] + B1[nb + 2];
            float s3 = a1[i][3] + B1[nb + 3];
            s0 = s0 / (1.f + __expf(-s0));
            s1 = s1 / (1.f + __expf(-s1));
            s2 = s2 / (1.f + __expf(-s2));
            s3 = s3 / (1.f + __expf(-s3));
            unsigned int lo = (unsigned int)f2bf(s0) | ((unsigned int)f2bf(s1) << 16);
            unsigned int hi = (unsigned int)f2bf(s2) | ((unsigned int)f2bf(s3) << 16);
            *(unsigned int*)&h1[(w * 16 + rl) * H1S + nb]     = lo;
            *(unsigned int*)&h1[(w * 16 + rl) * H1S + nb + 2] = hi;
        }

        // ---- stage W2 (128 x 64) into wl (all waves done reading W1)
        __syncthreads();
        #pragma unroll
        for (int c = tid; c < 1024; c += 256) {
            int pp = c >> 3, kc = c & 7;
            const float* src = W2 + (size_t)pp * 64 + kc * 8;
            *(uint4*)&wl[pp * W2S + kc * 8] =
                cvt8(((const float4*)src)[0], ((const float4*)src)[1]);
        }
        __syncthreads();

        // ---- GEMM2: D2[p=128][m=16/wave] = sum_j W2[p][j] h1[m][j], K=64
        short8 hf[2];
        #pragma unroll
        for (int ks = 0; ks < 2; ++ks)
            hf[ks] = *(const short8*)&h1[(w * 16 + rl) * H1S + ks * 32 + kgrp * 8];
        #pragma unroll
        for (int p = 0; p < 8; ++p) {
            floatx4 a2 = (floatx4){0.f, 0.f, 0.f, 0.f};
            #pragma unroll
            for (int ks = 0; ks < 2; ++ks) {
                short8 wf = *(const short8*)&wl[(p * 16 + rl) * W2S + ks * 32 + kgrp * 8];
                a2 = __builtin_amdgcn_mfma_f32_16x16x32_bf16(wf, hf[ks], a2, 0, 0, 0);
            }
            // residual: xb[m][pcol] += a2 + b2   (wave-local rows)
            int m = w * 16 + rl;
            #pragma unroll
            for (int reg = 0; reg < 4; ++reg) {
                int pcol = p * 16 + kgrp * 4 + reg;
                int idx  = m * XBS + pcol;
                float xv = bfbits2f(xb[idx]);
                xb[idx] = f2bf(xv + a2[reg] + B2[pcol]);
            }
        }
    }

    // ---- final: out = INV_SQRT_2 * (nbr_fea + x)   (xb rows wave-local)
    {
        int m = tid >> 2;
        int q = tid & 3;
        int e = row0 + m;
        if (e < N_EDGES) {
            const float4* nf = (const float4*)(nbr_fea + (size_t)e * NF + q * 32);
            float4* dst      = (float4*)(out + (size_t)e * NF + q * 32);
            #pragma unroll
            for (int t = 0; t < 8; ++t) {
                float4 f = nf[t];
                int col = q * 32 + 4 * t;
                dst[t] = make_float4(
                    INV_SQRT_2 * (f.x + bfbits2f(xb[m * XBS + col + 0])),
                    INV_SQRT_2 * (f.y + bfbits2f(xb[m * XBS + col + 1])),
                    INV_SQRT_2 * (f.z + bfbits2f(xb[m * XBS + col + 2])),
                    INV_SQRT_2 * (f.w + bfbits2f(xb[m * XBS + col + 3])));
            }
        }
    }
}

// ---------------- workspace layout (bytes) ----------------
//   [0,              524288)   segSum   (512*256 f32)  -> mean after finalize
//   [524288,        1048576)   segSumSq (512*256 f32)  -> scale after finalize
//   [1048576,      52248576)   s_acc    (100000*128 f32)
//   [52248576,     52648576)   c_acc    (100000 f32)
//   --- everything above zeroed each launch ---
//   [52648576,     52652672)   seg_start (513 i32, padded)
//   [52652672,    257452672)   h (400000*256 bf16)

extern "C" void kernel_launch(void* const* d_in, const int* in_sizes, int n_in,
                              void* d_out, int out_size, void* d_ws, size_t ws_size,
                              hipStream_t stream) {
    const float* nbr_fea       = (const float*)d_in[0];
    const float* angle_fea     = (const float*)d_in[1];
    const int*   angle_nbr_idx = (const int*)d_in[2];
    const int*   cai           = (const int*)d_in[4];
    const float* W_full        = (const float*)d_in[5];
    const float* W_mask        = (const float*)d_in[6];
    const float* cn_gamma      = (const float*)d_in[7];
    const float* cn_beta       = (const float*)d_in[8];
    const float* ln_core_g     = (const float*)d_in[9];
    const float* ln_core_b     = (const float*)d_in[10];
    const float* ln2_g         = (const float*)d_in[11];
    const float* ln2_b         = (const float*)d_in[12];
    const float* W1a           = (const float*)d_in[13];
    const float* b1a           = (const float*)d_in[14];
    const float* W2a           = (const float*)d_in[15];
    const float* b2a           = (const float*)d_in[16];
    const float* W1b           = (const float*)d_in[17];
    const float* b1b           = (const float*)d_in[18];
    const float* W2b           = (const float*)d_in[19];
    const float* b2b           = (const float*)d_in[20];
    float* out = (float*)d_out;

    char* ws = (char*)d_ws;
    float* segSum    = (float*)(ws + 0);
    float* segSumSq  = (float*)(ws + 524288);
    float* s_acc     = (float*)(ws + 1048576);
    float* c_acc     = (float*)(ws + 52248576);
    int*   seg_start = (int*)  (ws + 52648576);
    __hip_bfloat16* h = (__hip_bfloat16*)(ws + 52652672);

    hipMemsetAsync(ws, 0, 52648576, stream);

    seg_bounds<<<3, 256, 0, stream>>>(cai, seg_start);
    gemm_gather_mfma<<<N_ANGLES / 128, 512, 0, stream>>>(
        angle_fea, nbr_fea, angle_nbr_idx, W_full, h);
    seg_stats<<<dim3(N_CRYST, 4), 256, 0, stream>>>(h, seg_start, segSum, segSumSq);
    seg_finalize<<<N_CRYST, 256, 0, stream>>>(seg_start, segSum, segSumSq);
    angle_msg<<<N_ANGLES / 4, 256, 0, stream>>>(
        h, cai, angle_nbr_idx, segSum, segSumSq,
        cn_gamma, cn_beta, ln_core_g, ln_core_b, W_mask, s_acc, c_acc);
    edge_mlp_mfma<<<(N_EDGES + MT - 1) / MT, 256, 0, stream>>>(
        s_acc, c_acc, nbr_fea, ln2_g, ln2_b,
        W1a, b1a, W2a, b2a, W1b, b1b, W2b, b2b, out);
}